// Round 8
// baseline (502.711 us; speedup 1.0000x reference)
//
#include <hip/hip_runtime.h>

typedef __attribute__((ext_vector_type(8))) short short8;
typedef __attribute__((ext_vector_type(4))) float f32x4;
typedef unsigned short ushort_t;

#define T_SEQ 2048
#define D_DIM 1024
#define M_ROWS 8192
#define CT 32
#define NC (T_SEQ / CT)

__device__ __forceinline__ unsigned short f2bf_rne(float v) {
    unsigned int u = __float_as_uint(v);
    unsigned int r = (u + 0x7fffu + ((u >> 16) & 1u)) >> 16;
    return (unsigned short)r;
}
__device__ __forceinline__ float bf2f(unsigned short u) {
    return __uint_as_float(((unsigned int)u) << 16);
}
__device__ __forceinline__ int swz_col(int m, int k) {
    return (k & ~31) | ((((k >> 3) ^ (m >> 1)) & 3) << 3) | (k & 7);
}

__device__ __forceinline__ void gld16(const ushort_t* g, ushort_t* l) {
    __builtin_amdgcn_global_load_lds(
        (const __attribute__((address_space(1))) unsigned int*)g,
        (__attribute__((address_space(3))) unsigned int*)l, 16, 0, 0);
}

// ---------------- prep_all: all transposes + cvt_x + cvt_rows + bias init ----------------
__device__ __forceinline__ void transpose_job(const float* __restrict__ W, int K, int N,
                                              ushort_t* __restrict__ hi, int bx, int by,
                                              int tid, float (*tile)[33]) {
    int kt = by * 32, nt = bx * 32;
    int c = tid & 31, r0 = tid >> 5;
#pragma unroll
    for (int i = 0; i < 4; i++)
        tile[r0 + i * 8][c] = W[(long)(kt + r0 + i * 8) * N + nt + c];
    __syncthreads();
#pragma unroll
    for (int i = 0; i < 4; i++) {
        int n = r0 + i * 8;
        int m = nt + n;
        float v = tile[c][n];
        int q = ((c >> 3) ^ (m >> 1)) & 3;
        hi[(long)m * K + kt + (q << 3) + (c & 7)] = f2bf_rne(v);
    }
}

__global__ void prep_all(const float* __restrict__ W_mix, const float* __restrict__ W_out,
                         const float* __restrict__ W_gc, const float* __restrict__ W_gate,
                         const float* __restrict__ x_re, const float* __restrict__ x_im,
                         const float* __restrict__ b_out, const float* __restrict__ b_gate,
                         const float* __restrict__ b_gc,
                         ushort_t* __restrict__ WmixT, ushort_t* __restrict__ WcatT,
                         ushort_t* __restrict__ WgcbT, ushort_t* __restrict__ WgateT,
                         ushort_t* __restrict__ Wout_rows,
                         ushort_t* __restrict__ xcat_hi,
                         float* __restrict__ b_cat, float* __restrict__ b_eff) {
    __shared__ float tile[32][33];
    int bid = blockIdx.x;
    int tid = threadIdx.x;
    if (bid < 8192) {
        int g = bid * 256 + tid;
        int m = g >> 8, cidx = g & 255;
        int q = (cidx ^ (m >> 1)) & 3;
        int korig = ((cidx >> 2) << 5) + (q << 3);
        const float* src = (korig < 1024) ? (x_re + (long)m * 1024 + korig)
                                          : (x_im + (long)m * 1024 + korig - 1024);
        float4 v0 = *(const float4*)src;
        float4 v1 = *(const float4*)(src + 4);
        float vv[8] = {v0.x, v0.y, v0.z, v0.w, v1.x, v1.y, v1.z, v1.w};
        union { short8 v; ushort_t u[8]; } H;
#pragma unroll
        for (int j = 0; j < 8; j++) H.u[j] = f2bf_rne(vv[j]);
        *(short8*)&xcat_hi[(long)m * 2048 + cidx * 8] = H.v;
    } else if (bid < 12288) {
        int j = bid - 8192;
        transpose_job(W_mix, 2048, 2048, WmixT, j & 63, j >> 6, tid, tile);
    } else if (bid < 16384) {
        int j = bid - 12288;
        transpose_job(W_out, 2048, 2048, WcatT, j & 63, j >> 6, tid, tile);
    } else if (bid < 20480) {
        int j = bid - 16384;
        transpose_job(W_gc + 2048ull * 2048ull, 2048, 2048, WgcbT, j & 63, j >> 6, tid, tile);
    } else if (bid < 22528) {
        int j = bid - 20480;
        transpose_job(W_gate, 2048, 1024, WgateT, j & 31, j >> 5, tid, tile);
    } else if (bid < 24576) {
        int g = (bid - 22528) * 256 + tid;
        int m = g >> 8, cidx = g & 255;
        int q = (cidx ^ (m >> 1)) & 3;
        int korig = ((cidx >> 2) << 5) + (q << 3);
        const float* p = W_out + (long)m * 2048 + korig;
        float4 v0 = *(const float4*)p;
        float4 v1 = *(const float4*)(p + 4);
        float vv[8] = {v0.x, v0.y, v0.z, v0.w, v1.x, v1.y, v1.z, v1.w};
        union { short8 v; ushort_t u[8]; } H;
#pragma unroll
        for (int j2 = 0; j2 < 8; j2++) H.u[j2] = f2bf_rne(vv[j2]);
        *(short8*)&Wout_rows[(long)m * 2048 + cidx * 8] = H.v;
    } else {
        int idx = (bid - 24576) * 256 + tid;
        if (idx < 2048) b_cat[idx] = b_out[idx];
        else if (idx < 3072) b_cat[idx] = b_gate[idx - 2048];
        else if (idx < 5120) b_eff[idx - 3072] = b_gc[idx - 3072];
    }
}

// ---------------- k-sliced gemv with atomic reduce (out must be pre-initialized) ----------------
__global__ void gemv_atomic(const float* __restrict__ v, const float* __restrict__ W,
                            float* __restrict__ out, int K, int N) {
    int n = blockIdx.x * 256 + threadIdx.x;
    int kn = K >> 3;
    int k0 = blockIdx.y * kn;
    float s = 0.f;
    for (int k = k0; k < k0 + kn; k++) s += v[k] * W[(long)k * N + n];
    atomicAdd(&out[n], s);
}

// ---------------- GEMM: C = A @ B^T (+Cadd)(+bias)(out-mode), plain bf16 ----------------
// Tile 256x128, BK=32, 4 waves (2Mx2N), per-wave 128x64 (acc[8][4]).
// Double-buffered LDS (48 KB), stage-early 2-phase: vmcnt(0)+barrier -> stage(kt+1)
// -> ds_read -> setprio(1) 32 MFMA setprio(0).
// OUTMODE 0: f32. 1: f32 + sigmoid-gate for col0>=2048. 2: bf16 swizzled rows.
//         3: bf16 plain rows.
template <int OUTMODE, bool ADDM>
__global__ __launch_bounds__(256, 2) void gemm_bf16(
    const ushort_t* __restrict__ Ahi,
    const ushort_t* __restrict__ Bhi,
    const float* __restrict__ bias,
    const float* __restrict__ Cadd, int ldadd,
    void* __restrict__ Cout, long ldc, int K) {
    // A: rows 0..255 (256x32), B: rows 0..127 (128x32), per buffer
    __shared__ ushort_t lds[2][(256 + 128) * 32];

    const int tid = threadIdx.x;
    const int lane = tid & 63;
    const int wave = tid >> 6;
    const int wr = wave >> 1, wc = wave & 1;       // 2M x 2N wave grid
    const int lr = lane & 15, kc = lane >> 4;
    // XCD-aware bijective swizzle (nwg % 8 == 0 for all our grids)
    const int nwg = gridDim.x * gridDim.y;
    const int orig = blockIdx.y * gridDim.x + blockIdx.x;
    const int q8 = nwg >> 3;
    const int w = (orig & 7) * q8 + (orig >> 3);
    const int row0 = (w / gridDim.x) * 256, col0 = (w % gridDim.x) * 128;

    f32x4 acc[8][4] = {};

    auto stage = [&](int buf, int kt) {
        const long kbase = (long)kt * 32;
        // A: 1024 16B-chunks (256 rows x 4 chunks); 4 per thread
#pragma unroll
        for (int j = 0; j < 4; j++) {
            int c = j * 256 + tid;
            gld16(Ahi + (long)(row0 + (c >> 2)) * K + kbase + (c & 3) * 8,
                  &lds[buf][c * 8]);
        }
        // B: 512 chunks (128 rows x 4); 2 per thread
#pragma unroll
        for (int j = 0; j < 2; j++) {
            int c = j * 256 + tid;
            gld16(Bhi + (long)(col0 + (c >> 2)) * K + kbase + (c & 3) * 8,
                  &lds[buf][8192 + c * 8]);
        }
    };

    const int nkt = K >> 5;
    stage(0, 0);
    int cur = 0;
    for (int kt = 0; kt < nkt; kt++) {
        asm volatile("s_waitcnt vmcnt(0)" ::: "memory");
        __builtin_amdgcn_sched_barrier(0);
        __builtin_amdgcn_s_barrier();
        __builtin_amdgcn_sched_barrier(0);
        if (kt + 1 < nkt) stage(cur ^ 1, kt + 1);

        short8 ahi[8], bhi[4];
#pragma unroll
        for (int mi = 0; mi < 8; mi++) {
            int r = wr * 128 + mi * 16 + lr;
            int idx = (r * 32 + kc * 8) ^ (((r >> 1) & 3) << 3);
            ahi[mi] = *(const short8*)&lds[cur][idx];
        }
#pragma unroll
        for (int ni = 0; ni < 4; ni++) {
            int r = wc * 64 + ni * 16 + lr;
            int idx = (r * 32 + kc * 8) ^ (((r >> 1) & 3) << 3);
            bhi[ni] = *(const short8*)&lds[cur][8192 + idx];
        }
        __builtin_amdgcn_s_setprio(1);
#pragma unroll
        for (int mi = 0; mi < 8; mi++)
#pragma unroll
            for (int ni = 0; ni < 4; ni++)
                acc[mi][ni] = __builtin_amdgcn_mfma_f32_16x16x32_bf16(ahi[mi], bhi[ni], acc[mi][ni], 0, 0, 0);
        __builtin_amdgcn_s_setprio(0);
        cur ^= 1;
    }

    const bool gate_blk = (OUTMODE == 1) && (col0 >= 2048);
    float bv[4];
#pragma unroll
    for (int ni = 0; ni < 4; ni++) bv[ni] = bias ? bias[col0 + wc * 64 + ni * 16 + lr] : 0.f;
#pragma unroll
    for (int mi = 0; mi < 8; mi++) {
        int rbase = row0 + wr * 128 + mi * 16 + kc * 4;
#pragma unroll
        for (int ni = 0; ni < 4; ni++) {
            int c = col0 + wc * 64 + ni * 16 + lr;
#pragma unroll
            for (int i = 0; i < 4; i++) {
                float v = acc[mi][ni][i] + bv[ni];
                if constexpr (ADDM) v += Cadd[(long)(rbase + i) * ldadd + c];
                if constexpr (OUTMODE == 2) {
                    ((ushort_t*)Cout)[(long)(rbase + i) * ldc + swz_col(rbase + i, c)] = f2bf_rne(v);
                } else if constexpr (OUTMODE == 3) {
                    ((ushort_t*)Cout)[(long)(rbase + i) * ldc + c] = f2bf_rne(v);
                } else {
                    if constexpr (OUTMODE == 1) {
                        if (gate_blk) v = 0.98f / (1.0f + __expf(-v)) + 0.01f;
                    }
                    ((float*)Cout)[(long)(rbase + i) * ldc + c] = v;
                }
            }
        }
    }
}

// ---------------- scan ----------------
__device__ __forceinline__ void step_coefs(float lre, float lim, float dt,
                                           float& are, float& aim,
                                           float& fre, float& fim) {
    float zr = lre * dt, zi = lim * dt;
    float ex = __expf(zr);
    float er = ex - 1.0f;
    float hh = 0.5f * zi;
    float s = __sinf(hh), c = __cosf(hh);
    float s2s = 2.0f * s * s;
    float cy = 1.0f - s2s;
    float sy = 2.0f * s * c;
    are = ex * cy;
    aim = ex * sy;
    float nr = er * cy - s2s;
    float ni = ex * sy;
    float r2 = zr * zr + zi * zi;
    float pr, pi;
    if (r2 > 1e-14f) {
        float inv = 1.0f / r2;
        pr = (nr * zr + ni * zi) * inv;
        pi = (ni * zr - nr * zi) * inv;
    } else {
        pr = 1.0f + 0.5f * zr;
        pi = 0.5f * zi;
    }
    fre = dt * pr;
    fim = dt * pi;
}

__device__ __forceinline__ void lam_of(const float* dre, const float* dim, int d,
                                       float& lre, float& lim) {
    float x = dre[d];
    float sp = fmaxf(x, 0.0f) + log1pf(expf(-fabsf(x)));
    lre = -sp;
    lim = dim[d];
}

__global__ void scan_phase1(const ushort_t* __restrict__ x_in,
                            const float* __restrict__ dt_seq,
                            const float* __restrict__ decay_re,
                            const float* __restrict__ decay_im,
                            float4* __restrict__ S) {
    int gw = (blockIdx.x * blockDim.x + threadIdx.x) >> 6;
    int lane = threadIdx.x & 63;
    int d64 = gw & 15;
    int c = (gw >> 4) & (NC - 1);
    int b = gw >> 10;
    int d = d64 * 64 + lane;
    float lre, lim;
    lam_of(decay_re, decay_im, d, lre, lim);
    float Are = 1.f, Aim = 0.f, Bre = 0.f, Bim = 0.f;
    for (int j = 0; j < CT; j++) {
        int t = c * CT + j;
        float dt = dt_seq[b * T_SEQ + t];
        float are, aim, fre, fim;
        step_coefs(lre, lim, dt, are, aim, fre, fim);
        size_t off = ((size_t)(b * T_SEQ + t)) * 2048;
        float xr = bf2f(x_in[off + d]);
        float xi = bf2f(x_in[off + 1024 + d]);
        float xsr = xr * fre - xi * fim;
        float xsi = xr * fim + xi * fre;
        float nbr = are * Bre - aim * Bim + xsr;
        float nbi = are * Bim + aim * Bre + xsi;
        Bre = nbr; Bim = nbi;
        float nar = are * Are - aim * Aim;
        float nai = are * Aim + aim * Are;
        Are = nar; Aim = nai;
    }
    S[(size_t)(b * NC + c) * D_DIM + d] = make_float4(Are, Aim, Bre, Bim);
}

__global__ void scan_phase2(const float4* __restrict__ S,
                            const float* __restrict__ h0_re,
                            const float* __restrict__ h0_im,
                            float2* __restrict__ Pre) {
    int idx = blockIdx.x * blockDim.x + threadIdx.x;
    int b = idx >> 10, d = idx & 1023;
    float Are = 1.f, Aim = 0.f;
    float Bre = h0_re[d], Bim = h0_im[d];
    for (int c = 0; c < NC; c++) {
        Pre[(size_t)(b * NC + c) * D_DIM + d] = make_float2(Bre, Bim);
        float4 s = S[(size_t)(b * NC + c) * D_DIM + d];
        float nAre = s.x * Are - s.y * Aim;
        float nAim = s.x * Aim + s.y * Are;
        float nBre = s.x * Bre - s.y * Bim + s.z;
        float nBim = s.x * Bim + s.y * Bre + s.w;
        Are = nAre; Aim = nAim; Bre = nBre; Bim = nBim;
    }
}

__global__ void scan_phase3(const ushort_t* __restrict__ x_in,
                            const float* __restrict__ dt_seq,
                            const float* __restrict__ decay_re,
                            const float* __restrict__ decay_im,
                            const float2* __restrict__ Pre,
                            ushort_t* __restrict__ sthi) {
    int gw = (blockIdx.x * blockDim.x + threadIdx.x) >> 6;
    int lane = threadIdx.x & 63;
    int d64 = gw & 15;
    int c = (gw >> 4) & (NC - 1);
    int b = gw >> 10;
    int d = d64 * 64 + lane;
    float lre, lim;
    lam_of(decay_re, decay_im, d, lre, lim);
    float2 h = Pre[(size_t)(b * NC + c) * D_DIM + d];
    float hre = h.x, him = h.y;
    for (int j = 0; j < CT; j++) {
        int t = c * CT + j;
        int m = b * T_SEQ + t;
        float dt = dt_seq[m];
        float are, aim, fre, fim;
        step_coefs(lre, lim, dt, are, aim, fre, fim);
        size_t off = ((size_t)m) * 2048;
        float xr = bf2f(x_in[off + d]);
        float xi = bf2f(x_in[off + 1024 + d]);
        float xsr = xr * fre - xi * fim;
        float xsi = xr * fim + xi * fre;
        float nre = are * hre - aim * him + xsr;
        float nim = are * him + aim * hre + xsi;
        hre = nre; him = nim;
        long idx = (long)m * 2048 + swz_col(m, d);
        sthi[idx] = f2bf_rne(hre);
        sthi[idx + 1024] = f2bf_rne(him);
    }
}

extern "C" void kernel_launch(void* const* d_in, const int* in_sizes, int n_in,
                              void* d_out, int out_size, void* d_ws, size_t ws_size,
                              hipStream_t stream) {
    const float* x_re = (const float*)d_in[0];
    const float* x_im = (const float*)d_in[1];
    const float* dt_seq = (const float*)d_in[2];
    const float* decay_re = (const float*)d_in[3];
    const float* decay_im = (const float*)d_in[4];
    const float* h0_re = (const float*)d_in[5];
    const float* h0_im = (const float*)d_in[6];
    const float* W_mix = (const float*)d_in[7];
    const float* b_mix = (const float*)d_in[8];
    const float* W_out = (const float*)d_in[9];
    const float* b_out = (const float*)d_in[10];
    const float* W_gc = (const float*)d_in[11];
    const float* b_gc = (const float*)d_in[12];
    const float* W_gate = (const float*)d_in[13];
    const float* b_gate = (const float*)d_in[14];
    float* out = (float*)d_out;

    char* ws = (char*)d_ws;
    const unsigned long MB = 1048576ull;
    ushort_t* x_inb = (ushort_t*)ws;                   // 32 MB (bf16 x_in)
    ushort_t* Wout_rows = (ushort_t*)(ws + 32 * MB);   // 8 MB
    ushort_t* WgcbT = (ushort_t*)(ws + 40 * MB);       // 8 MB
    ushort_t* WgateT = (ushort_t*)(ws + 48 * MB);      // 4 MB
    ushort_t* tmp1_hi = (ushort_t*)(ws + 52 * MB);     // 8 MB
    ushort_t* xcat_hi = (ushort_t*)(ws + 64 * MB);     // 32 MB
    ushort_t* state_hi = xcat_hi;                      // time-aliased
    float4* S = (float4*)(ws + 128 * MB);              // 4 MB
    float2* Pre = (float2*)(ws + 132 * MB);            // 2 MB
    ushort_t* WmixT = (ushort_t*)(ws + 134 * MB);      // 8 MB
    ushort_t* WcatT = (ushort_t*)(ws + 142 * MB);      // 12 MB (3072 x 2048)
    float* b_cat = (float*)(ws + 154 * MB);            // 12 KB
    float* b_eff = (float*)(ws + 154 * MB + 16384);    // 8 KB

    dim3 blk(256);

    // 1. all transposes/conversions/bias-inits in one launch
    prep_all<<<dim3(24596), blk, 0, stream>>>(
        W_mix, W_out, W_gc, W_gate, x_re, x_im, b_out, b_gate, b_gc,
        WmixT, WcatT, WgcbT, WgateT, Wout_rows, xcat_hi, b_cat, b_eff);

    // 2. b_eff += b_out @ W_gc_bot   (b_eff pre-init to b_gc)
    gemv_atomic<<<dim3(8, 8), blk, 0, stream>>>(b_out, W_gc + 2048ull * 2048ull, b_eff, 2048, 2048);

    // 3. tmp1 = W_out @ W_gc_bot + W_gc_top  -> bf16 swizzled rows (M=2048, N=2048)
    gemm_bf16<2, true><<<dim3(16, 8), blk, 0, stream>>>(
        Wout_rows, WgcbT, nullptr, W_gc, 2048, tmp1_hi, 2048, 2048);

    // 4. W_totalT = W_gateT @ tmp1T  -> WcatT rows 2048..3071 (M=1024, N=2048)
    gemm_bf16<2, false><<<dim3(16, 4), blk, 0, stream>>>(
        WgateT, tmp1_hi, nullptr, nullptr, 0,
        WcatT + 2048ull * 2048ull, 2048, 2048);

    // 5. b_cat[2048:] += b_eff @ W_gate   (pre-init to b_gate)
    gemv_atomic<<<dim3(4, 8), blk, 0, stream>>>(b_eff, W_gate, b_cat + 2048, 2048, 1024);

    // 6. x_in(bf16) = xcat @ W_mix + b_mix   (M=8192, N=2048)
    gemm_bf16<3, false><<<dim3(16, 32), blk, 0, stream>>>(
        xcat_hi, WmixT, b_mix, nullptr, 0, x_inb, 2048, 2048);

    // 7-9. scan
    scan_phase1<<<dim3(1024), blk, 0, stream>>>(x_inb, dt_seq, decay_re, decay_im, S);
    scan_phase2<<<dim3(16), blk, 0, stream>>>(S, h0_re, h0_im, Pre);
    scan_phase3<<<dim3(1024), blk, 0, stream>>>(x_inb, dt_seq, decay_re, decay_im, Pre,
                                                state_hi);

    // 10. [src | gate] = state @ [W_outT | W_totalT]^T + b_cat   (M=8192, N=3072)
    gemm_bf16<1, false><<<dim3(24, 32), blk, 0, stream>>>(
        state_hi, WcatT, b_cat, nullptr, 0, out, 3072, 2048);
}

// Round 10
// 491.317 us; speedup vs baseline: 1.0232x; 1.0232x over previous
//
#include <hip/hip_runtime.h>

typedef __attribute__((ext_vector_type(8))) short short8;
typedef __attribute__((ext_vector_type(4))) float f32x4;
typedef unsigned short ushort_t;

#define T_SEQ 2048
#define D_DIM 1024
#define M_ROWS 8192
#define CT 32
#define NC (T_SEQ / CT)

__device__ __forceinline__ unsigned short f2bf_rne(float v) {
    unsigned int u = __float_as_uint(v);
    unsigned int r = (u + 0x7fffu + ((u >> 16) & 1u)) >> 16;
    return (unsigned short)r;
}
__device__ __forceinline__ float bf2f(unsigned short u) {
    return __uint_as_float(((unsigned int)u) << 16);
}
__device__ __forceinline__ int swz_col(int m, int k) {
    return (k & ~31) | ((((k >> 3) ^ (m >> 1)) & 3) << 3) | (k & 7);
}

__device__ __forceinline__ void gld16(const ushort_t* g, ushort_t* l) {
    __builtin_amdgcn_global_load_lds(
        (const __attribute__((address_space(1))) unsigned int*)g,
        (__attribute__((address_space(3))) unsigned int*)l, 16, 0, 0);
}

// ---------------- prep_all: all transposes + cvt_x + cvt_rows + bias init ----------------
// transpose with 16B vectorized swizzled writes: 32 rows x 4 chunks = 128 jobs
__device__ __forceinline__ void transpose_job(const float* __restrict__ W, int K, int N,
                                              ushort_t* __restrict__ hi, int bx, int by,
                                              int tid, float (*tile)[33]) {
    int kt = by * 32, nt = bx * 32;
    int c = tid & 31, r0 = tid >> 5;
#pragma unroll
    for (int i = 0; i < 4; i++)
        tile[r0 + i * 8][c] = W[(long)(kt + r0 + i * 8) * N + nt + c];
    __syncthreads();
    if (tid < 128) {
        int m_l = tid >> 2, kc8 = tid & 3;   // m_l 0..31, kc8 0..3
        int m = nt + m_l;
        int q = (kc8 ^ (m >> 1)) & 3;
        union { short8 v; ushort_t u[8]; } H;
#pragma unroll
        for (int j = 0; j < 8; j++) H.u[j] = f2bf_rne(tile[kc8 * 8 + j][m_l]);
        *(short8*)&hi[(long)m * K + kt + (q << 3)] = H.v;
    }
}

__global__ void prep_all(const float* __restrict__ W_mix, const float* __restrict__ W_out,
                         const float* __restrict__ W_gc, const float* __restrict__ W_gate,
                         const float* __restrict__ x_re, const float* __restrict__ x_im,
                         const float* __restrict__ b_out, const float* __restrict__ b_gate,
                         const float* __restrict__ b_gc,
                         ushort_t* __restrict__ WmixT, ushort_t* __restrict__ WcatT,
                         ushort_t* __restrict__ WgcbT, ushort_t* __restrict__ WgateT,
                         ushort_t* __restrict__ Wout_rows,
                         ushort_t* __restrict__ xcat_hi,
                         float* __restrict__ b_cat, float* __restrict__ b_eff) {
    __shared__ float tile[32][33];
    int bid = blockIdx.x;
    int tid = threadIdx.x;
    if (bid < 8192) {
        int g = bid * 256 + tid;
        int m = g >> 8, cidx = g & 255;
        int q = (cidx ^ (m >> 1)) & 3;
        int korig = ((cidx >> 2) << 5) + (q << 3);
        const float* src = (korig < 1024) ? (x_re + (long)m * 1024 + korig)
                                          : (x_im + (long)m * 1024 + korig - 1024);
        float4 v0 = *(const float4*)src;
        float4 v1 = *(const float4*)(src + 4);
        float vv[8] = {v0.x, v0.y, v0.z, v0.w, v1.x, v1.y, v1.z, v1.w};
        union { short8 v; ushort_t u[8]; } H;
#pragma unroll
        for (int j = 0; j < 8; j++) H.u[j] = f2bf_rne(vv[j]);
        *(short8*)&xcat_hi[(long)m * 2048 + cidx * 8] = H.v;
    } else if (bid < 12288) {
        int j = bid - 8192;
        transpose_job(W_mix, 2048, 2048, WmixT, j & 63, j >> 6, tid, tile);
    } else if (bid < 16384) {
        int j = bid - 12288;
        transpose_job(W_out, 2048, 2048, WcatT, j & 63, j >> 6, tid, tile);
    } else if (bid < 20480) {
        int j = bid - 16384;
        transpose_job(W_gc + 2048ull * 2048ull, 2048, 2048, WgcbT, j & 63, j >> 6, tid, tile);
    } else if (bid < 22528) {
        int j = bid - 20480;
        transpose_job(W_gate, 2048, 1024, WgateT, j & 31, j >> 5, tid, tile);
    } else if (bid < 24576) {
        int g = (bid - 22528) * 256 + tid;
        int m = g >> 8, cidx = g & 255;
        int q = (cidx ^ (m >> 1)) & 3;
        int korig = ((cidx >> 2) << 5) + (q << 3);
        const float* p = W_out + (long)m * 2048 + korig;
        float4 v0 = *(const float4*)p;
        float4 v1 = *(const float4*)(p + 4);
        float vv[8] = {v0.x, v0.y, v0.z, v0.w, v1.x, v1.y, v1.z, v1.w};
        union { short8 v; ushort_t u[8]; } H;
#pragma unroll
        for (int j2 = 0; j2 < 8; j2++) H.u[j2] = f2bf_rne(vv[j2]);
        *(short8*)&Wout_rows[(long)m * 2048 + cidx * 8] = H.v;
    } else {
        int idx = (bid - 24576) * 256 + tid;
        if (idx < 2048) b_cat[idx] = b_out[idx];
        else if (idx < 3072) b_cat[idx] = b_gate[idx - 2048];
        else if (idx < 5120) b_eff[idx - 3072] = b_gc[idx - 3072];
    }
}

// ---------------- k-sliced gemv with atomic reduce (out must be pre-initialized) ----------------
__global__ void gemv_atomic(const float* __restrict__ v, const float* __restrict__ W,
                            float* __restrict__ out, int K, int N) {
    int n = blockIdx.x * 256 + threadIdx.x;
    int kn = K >> 3;
    int k0 = blockIdx.y * kn;
    float s = 0.f;
    for (int k = k0; k < k0 + kn; k++) s += v[k] * W[(long)k * N + n];
    atomicAdd(&out[n], s);
}

// ---------------- GEMM: C = A @ B^T (+Cadd)(+bias)(out-mode), plain bf16 ----------------
// Tile 256x128, BK=32, 4 waves (2Mx2N), per-wave 128x64 (acc[8][4]).
// 3-buffer LDS rotation (72 KB), counted vmcnt(6), one raw barrier per K-step,
// prefetch depth 2, setprio around the 32-MFMA cluster.
// OUTMODE 0: f32. 1: f32 + sigmoid-gate for col0>=2048. 2: bf16 swizzled rows.
//         3: bf16 plain rows.
template <int OUTMODE, bool ADDM>
__global__ __launch_bounds__(256, 2) void gemm_bf16(
    const ushort_t* __restrict__ Ahi,
    const ushort_t* __restrict__ Bhi,
    const float* __restrict__ bias,
    const float* __restrict__ Cadd, int ldadd,
    void* __restrict__ Cout, long ldc, int K) {
    // per buffer: A 256x32 (16 KB) + B 128x32 (8 KB) = 12288 ushorts
    __shared__ ushort_t lds[3][12288];

    const int tid = threadIdx.x;
    const int lane = tid & 63;
    const int wave = tid >> 6;
    const int wr = wave >> 1, wc = wave & 1;       // 2M x 2N wave grid
    const int lr = lane & 15, kc = lane >> 4;
    // XCD-aware bijective swizzle (nwg % 8 == 0 for all our grids)
    const int nwg = gridDim.x * gridDim.y;
    const int orig = blockIdx.y * gridDim.x + blockIdx.x;
    const int q8 = nwg >> 3;
    const int w = (orig & 7) * q8 + (orig >> 3);
    const int row0 = (w / gridDim.x) * 256, col0 = (w % gridDim.x) * 128;

    f32x4 acc[8][4] = {};

    auto stage = [&](int buf, int kt) {
        const long kbase = (long)kt * 32;
        // A: 1024 16B-chunks (256 rows x 4 chunks); 4 per thread
#pragma unroll
        for (int j = 0; j < 4; j++) {
            int c = j * 256 + tid;
            gld16(Ahi + (long)(row0 + (c >> 2)) * K + kbase + (c & 3) * 8,
                  &lds[buf][c * 8]);
        }
        // B: 512 chunks (128 rows x 4); 2 per thread
#pragma unroll
        for (int j = 0; j < 2; j++) {
            int c = j * 256 + tid;
            gld16(Bhi + (long)(col0 + (c >> 2)) * K + kbase + (c & 3) * 8,
                  &lds[buf][8192 + c * 8]);
        }
    };

    const int nkt = K >> 5;
    stage(0, 0);
    stage(1, 1);
    int cur = 0;
    for (int kt = 0; kt < nkt; kt++) {
        if (kt + 1 < nkt) {
            asm volatile("s_waitcnt vmcnt(6)" ::: "memory");  // tile kt landed; kt+1's 6 in flight
        } else {
            asm volatile("s_waitcnt vmcnt(0)" ::: "memory");
        }
        __builtin_amdgcn_sched_barrier(0);
        __builtin_amdgcn_s_barrier();
        __builtin_amdgcn_sched_barrier(0);
        if (kt + 2 < nkt) stage((cur + 2) % 3, kt + 2);

        short8 ahi[8], bhi[4];
#pragma unroll
        for (int mi = 0; mi < 8; mi++) {
            int r = wr * 128 + mi * 16 + lr;
            int idx = (r * 32 + kc * 8) ^ (((r >> 1) & 3) << 3);
            ahi[mi] = *(const short8*)&lds[cur][idx];
        }
#pragma unroll
        for (int ni = 0; ni < 4; ni++) {
            int r = wc * 64 + ni * 16 + lr;
            int idx = (r * 32 + kc * 8) ^ (((r >> 1) & 3) << 3);
            bhi[ni] = *(const short8*)&lds[cur][8192 + idx];
        }
        __builtin_amdgcn_s_setprio(1);
#pragma unroll
        for (int mi = 0; mi < 8; mi++)
#pragma unroll
            for (int ni = 0; ni < 4; ni++)
                acc[mi][ni] = __builtin_amdgcn_mfma_f32_16x16x32_bf16(ahi[mi], bhi[ni], acc[mi][ni], 0, 0, 0);
        __builtin_amdgcn_s_setprio(0);
        cur = (cur + 1) % 3;
    }

    const bool gate_blk = (OUTMODE == 1) && (col0 >= 2048);
    float bv[4];
#pragma unroll
    for (int ni = 0; ni < 4; ni++) bv[ni] = bias ? bias[col0 + wc * 64 + ni * 16 + lr] : 0.f;
#pragma unroll
    for (int mi = 0; mi < 8; mi++) {
        int rbase = row0 + wr * 128 + mi * 16 + kc * 4;
#pragma unroll
        for (int ni = 0; ni < 4; ni++) {
            int c = col0 + wc * 64 + ni * 16 + lr;
#pragma unroll
            for (int i = 0; i < 4; i++) {
                float v = acc[mi][ni][i] + bv[ni];
                if constexpr (ADDM) v += Cadd[(long)(rbase + i) * ldadd + c];
                if constexpr (OUTMODE == 2) {
                    ((ushort_t*)Cout)[(long)(rbase + i) * ldc + swz_col(rbase + i, c)] = f2bf_rne(v);
                } else if constexpr (OUTMODE == 3) {
                    ((ushort_t*)Cout)[(long)(rbase + i) * ldc + c] = f2bf_rne(v);
                } else {
                    if constexpr (OUTMODE == 1) {
                        if (gate_blk) v = 0.98f / (1.0f + __expf(-v)) + 0.01f;
                    }
                    ((float*)Cout)[(long)(rbase + i) * ldc + c] = v;
                }
            }
        }
    }
}

// ---------------- scan ----------------
__device__ __forceinline__ void step_coefs(float lre, float lim, float dt,
                                           float& are, float& aim,
                                           float& fre, float& fim) {
    float zr = lre * dt, zi = lim * dt;
    float ex = __expf(zr);
    float er = ex - 1.0f;
    float hh = 0.5f * zi;
    float s = __sinf(hh), c = __cosf(hh);
    float s2s = 2.0f * s * s;
    float cy = 1.0f - s2s;
    float sy = 2.0f * s * c;
    are = ex * cy;
    aim = ex * sy;
    float nr = er * cy - s2s;
    float ni = ex * sy;
    float r2 = zr * zr + zi * zi;
    float pr, pi;
    if (r2 > 1e-14f) {
        float inv = 1.0f / r2;
        pr = (nr * zr + ni * zi) * inv;
        pi = (ni * zr - nr * zi) * inv;
    } else {
        pr = 1.0f + 0.5f * zr;
        pi = 0.5f * zi;
    }
    fre = dt * pr;
    fim = dt * pi;
}

__device__ __forceinline__ void lam_of(const float* dre, const float* dim, int d,
                                       float& lre, float& lim) {
    float x = dre[d];
    float sp = fmaxf(x, 0.0f) + log1pf(expf(-fabsf(x)));
    lre = -sp;
    lim = dim[d];
}

__global__ void scan_phase1(const ushort_t* __restrict__ x_in,
                            const float* __restrict__ dt_seq,
                            const float* __restrict__ decay_re,
                            const float* __restrict__ decay_im,
                            float4* __restrict__ S) {
    int gw = (blockIdx.x * blockDim.x + threadIdx.x) >> 6;
    int lane = threadIdx.x & 63;
    int d64 = gw & 15;
    int c = (gw >> 4) & (NC - 1);
    int b = gw >> 10;
    int d = d64 * 64 + lane;
    float lre, lim;
    lam_of(decay_re, decay_im, d, lre, lim);
    float Are = 1.f, Aim = 0.f, Bre = 0.f, Bim = 0.f;
    for (int j = 0; j < CT; j++) {
        int t = c * CT + j;
        float dt = dt_seq[b * T_SEQ + t];
        float are, aim, fre, fim;
        step_coefs(lre, lim, dt, are, aim, fre, fim);
        size_t off = ((size_t)(b * T_SEQ + t)) * 2048;
        float xr = bf2f(x_in[off + d]);
        float xi = bf2f(x_in[off + 1024 + d]);
        float xsr = xr * fre - xi * fim;
        float xsi = xr * fim + xi * fre;
        float nbr = are * Bre - aim * Bim + xsr;
        float nbi = are * Bim + aim * Bre + xsi;
        Bre = nbr; Bim = nbi;
        float nar = are * Are - aim * Aim;
        float nai = are * Aim + aim * Are;
        Are = nar; Aim = nai;
    }
    S[(size_t)(b * NC + c) * D_DIM + d] = make_float4(Are, Aim, Bre, Bim);
}

__global__ void scan_phase2(const float4* __restrict__ S,
                            const float* __restrict__ h0_re,
                            const float* __restrict__ h0_im,
                            float2* __restrict__ Pre) {
    int idx = blockIdx.x * blockDim.x + threadIdx.x;
    int b = idx >> 10, d = idx & 1023;
    float Are = 1.f, Aim = 0.f;
    float Bre = h0_re[d], Bim = h0_im[d];
    for (int c = 0; c < NC; c++) {
        Pre[(size_t)(b * NC + c) * D_DIM + d] = make_float2(Bre, Bim);
        float4 s = S[(size_t)(b * NC + c) * D_DIM + d];
        float nAre = s.x * Are - s.y * Aim;
        float nAim = s.x * Aim + s.y * Are;
        float nBre = s.x * Bre - s.y * Bim + s.z;
        float nBim = s.x * Bim + s.y * Bre + s.w;
        Are = nAre; Aim = nAim; Bre = nBre; Bim = nBim;
    }
}

__global__ void scan_phase3(const ushort_t* __restrict__ x_in,
                            const float* __restrict__ dt_seq,
                            const float* __restrict__ decay_re,
                            const float* __restrict__ decay_im,
                            const float2* __restrict__ Pre,
                            ushort_t* __restrict__ sthi) {
    int gw = (blockIdx.x * blockDim.x + threadIdx.x) >> 6;
    int lane = threadIdx.x & 63;
    int d64 = gw & 15;
    int c = (gw >> 4) & (NC - 1);
    int b = gw >> 10;
    int d = d64 * 64 + lane;
    float lre, lim;
    lam_of(decay_re, decay_im, d, lre, lim);
    float2 h = Pre[(size_t)(b * NC + c) * D_DIM + d];
    float hre = h.x, him = h.y;
    for (int j = 0; j < CT; j++) {
        int t = c * CT + j;
        int m = b * T_SEQ + t;
        float dt = dt_seq[m];
        float are, aim, fre, fim;
        step_coefs(lre, lim, dt, are, aim, fre, fim);
        size_t off = ((size_t)m) * 2048;
        float xr = bf2f(x_in[off + d]);
        float xi = bf2f(x_in[off + 1024 + d]);
        float xsr = xr * fre - xi * fim;
        float xsi = xr * fim + xi * fre;
        float nre = are * hre - aim * him + xsr;
        float nim = are * him + aim * hre + xsi;
        hre = nre; him = nim;
        long idx = (long)m * 2048 + swz_col(m, d);
        sthi[idx] = f2bf_rne(hre);
        sthi[idx + 1024] = f2bf_rne(him);
    }
}

extern "C" void kernel_launch(void* const* d_in, const int* in_sizes, int n_in,
                              void* d_out, int out_size, void* d_ws, size_t ws_size,
                              hipStream_t stream) {
    const float* x_re = (const float*)d_in[0];
    const float* x_im = (const float*)d_in[1];
    const float* dt_seq = (const float*)d_in[2];
    const float* decay_re = (const float*)d_in[3];
    const float* decay_im = (const float*)d_in[4];
    const float* h0_re = (const float*)d_in[5];
    const float* h0_im = (const float*)d_in[6];
    const float* W_mix = (const float*)d_in[7];
    const float* b_mix = (const float*)d_in[8];
    const float* W_out = (const float*)d_in[9];
    const float* b_out = (const float*)d_in[10];
    const float* W_gc = (const float*)d_in[11];
    const float* b_gc = (const float*)d_in[12];
    const float* W_gate = (const float*)d_in[13];
    const float* b_gate = (const float*)d_in[14];
    float* out = (float*)d_out;

    char* ws = (char*)d_ws;
    const unsigned long MB = 1048576ull;
    ushort_t* x_inb = (ushort_t*)ws;                   // 32 MB (bf16 x_in)
    ushort_t* Wout_rows = (ushort_t*)(ws + 32 * MB);   // 8 MB
    ushort_t* WgcbT = (ushort_t*)(ws + 40 * MB);       // 8 MB
    ushort_t* WgateT = (ushort_t*)(ws + 48 * MB);      // 4 MB
    ushort_t* tmp1_hi = (ushort_t*)(ws + 52 * MB);     // 8 MB
    ushort_t* xcat_hi = (ushort_t*)(ws + 64 * MB);     // 32 MB
    ushort_t* state_hi = xcat_hi;                      // time-aliased
    float4* S = (float4*)(ws + 128 * MB);              // 4 MB
    float2* Pre = (float2*)(ws + 132 * MB);            // 2 MB
    ushort_t* WmixT = (ushort_t*)(ws + 134 * MB);      // 8 MB
    ushort_t* WcatT = (ushort_t*)(ws + 142 * MB);      // 12 MB (3072 x 2048)
    float* b_cat = (float*)(ws + 154 * MB);            // 12 KB
    float* b_eff = (float*)(ws + 154 * MB + 16384);    // 8 KB

    dim3 blk(256);

    // 1. all transposes/conversions/bias-inits in one launch
    prep_all<<<dim3(24596), blk, 0, stream>>>(
        W_mix, W_out, W_gc, W_gate, x_re, x_im, b_out, b_gate, b_gc,
        WmixT, WcatT, WgcbT, WgateT, Wout_rows, xcat_hi, b_cat, b_eff);

    // 2. b_eff += b_out @ W_gc_bot   (b_eff pre-init to b_gc)
    gemv_atomic<<<dim3(8, 8), blk, 0, stream>>>(b_out, W_gc + 2048ull * 2048ull, b_eff, 2048, 2048);

    // 3. tmp1 = W_out @ W_gc_bot + W_gc_top  -> bf16 swizzled rows (M=2048, N=2048)
    gemm_bf16<2, true><<<dim3(16, 8), blk, 0, stream>>>(
        Wout_rows, WgcbT, nullptr, W_gc, 2048, tmp1_hi, 2048, 2048);

    // 4. W_totalT = W_gateT @ tmp1T  -> WcatT rows 2048..3071 (M=1024, N=2048)
    gemm_bf16<2, false><<<dim3(16, 4), blk, 0, stream>>>(
        WgateT, tmp1_hi, nullptr, nullptr, 0,
        WcatT + 2048ull * 2048ull, 2048, 2048);

    // 5. b_cat[2048:] += b_eff @ W_gate   (pre-init to b_gate)
    gemv_atomic<<<dim3(4, 8), blk, 0, stream>>>(b_eff, W_gate, b_cat + 2048, 2048, 1024);

    // 6. x_in(bf16) = xcat @ W_mix + b_mix   (M=8192, N=2048)
    gemm_bf16<3, false><<<dim3(16, 32), blk, 0, stream>>>(
        xcat_hi, WmixT, b_mix, nullptr, 0, x_inb, 2048, 2048);

    // 7-9. scan
    scan_phase1<<<dim3(1024), blk, 0, stream>>>(x_inb, dt_seq, decay_re, decay_im, S);
    scan_phase2<<<dim3(16), blk, 0, stream>>>(S, h0_re, h0_im, Pre);
    scan_phase3<<<dim3(1024), blk, 0, stream>>>(x_inb, dt_seq, decay_re, decay_im, Pre,
                                                state_hi);

    // 10. [src | gate] = state @ [W_outT | W_totalT]^T + b_cat   (M=8192, N=3072)
    gemm_bf16<1, false><<<dim3(24, 32), blk, 0, stream>>>(
        state_hi, WcatT, b_cat, nullptr, 0, out, 3072, 2048);
}

// Round 11
// 490.595 us; speedup vs baseline: 1.0247x; 1.0015x over previous
//
#include <hip/hip_runtime.h>

typedef __attribute__((ext_vector_type(8))) short short8;
typedef __attribute__((ext_vector_type(4))) float f32x4;
typedef unsigned short ushort_t;

#define T_SEQ 2048
#define D_DIM 1024
#define M_ROWS 8192
#define CT 32
#define NC (T_SEQ / CT)

__device__ __forceinline__ unsigned short f2bf_rne(float v) {
    unsigned int u = __float_as_uint(v);
    unsigned int r = (u + 0x7fffu + ((u >> 16) & 1u)) >> 16;
    return (unsigned short)r;
}
__device__ __forceinline__ float bf2f(unsigned short u) {
    return __uint_as_float(((unsigned int)u) << 16);
}
__device__ __forceinline__ int swz_col(int m, int k) {
    return (k & ~31) | ((((k >> 3) ^ (m >> 1)) & 3) << 3) | (k & 7);
}

__device__ __forceinline__ void gld16(const ushort_t* g, ushort_t* l) {
    __builtin_amdgcn_global_load_lds(
        (const __attribute__((address_space(1))) unsigned int*)g,
        (__attribute__((address_space(3))) unsigned int*)l, 16, 0, 0);
}

// ---------------- prep_all: all transposes + cvt_x + cvt_rows + bias init ----------------
__device__ __forceinline__ void transpose_job(const float* __restrict__ W, int K, int N,
                                              ushort_t* __restrict__ hi, int bx, int by,
                                              int tid, float (*tile)[33]) {
    int kt = by * 32, nt = bx * 32;
    int c = tid & 31, r0 = tid >> 5;
#pragma unroll
    for (int i = 0; i < 4; i++)
        tile[r0 + i * 8][c] = W[(long)(kt + r0 + i * 8) * N + nt + c];
    __syncthreads();
    if (tid < 128) {
        int m_l = tid >> 2, kc8 = tid & 3;   // m_l 0..31, kc8 0..3
        int m = nt + m_l;
        int q = (kc8 ^ (m >> 1)) & 3;
        union { short8 v; ushort_t u[8]; } H;
#pragma unroll
        for (int j = 0; j < 8; j++) H.u[j] = f2bf_rne(tile[kc8 * 8 + j][m_l]);
        *(short8*)&hi[(long)m * K + kt + (q << 3)] = H.v;
    }
}

__global__ void prep_all(const float* __restrict__ W_mix, const float* __restrict__ W_out,
                         const float* __restrict__ W_gc, const float* __restrict__ W_gate,
                         const float* __restrict__ x_re, const float* __restrict__ x_im,
                         const float* __restrict__ b_out, const float* __restrict__ b_gate,
                         const float* __restrict__ b_gc,
                         ushort_t* __restrict__ WmixT, ushort_t* __restrict__ WcatT,
                         ushort_t* __restrict__ WgcbT, ushort_t* __restrict__ WgateT,
                         ushort_t* __restrict__ Wout_rows,
                         ushort_t* __restrict__ xcat_hi,
                         float* __restrict__ b_cat, float* __restrict__ b_eff) {
    __shared__ float tile[32][33];
    int bid = blockIdx.x;
    int tid = threadIdx.x;
    if (bid < 8192) {
        int g = bid * 256 + tid;
        int m = g >> 8, cidx = g & 255;
        int q = (cidx ^ (m >> 1)) & 3;
        int korig = ((cidx >> 2) << 5) + (q << 3);
        const float* src = (korig < 1024) ? (x_re + (long)m * 1024 + korig)
                                          : (x_im + (long)m * 1024 + korig - 1024);
        float4 v0 = *(const float4*)src;
        float4 v1 = *(const float4*)(src + 4);
        float vv[8] = {v0.x, v0.y, v0.z, v0.w, v1.x, v1.y, v1.z, v1.w};
        union { short8 v; ushort_t u[8]; } H;
#pragma unroll
        for (int j = 0; j < 8; j++) H.u[j] = f2bf_rne(vv[j]);
        *(short8*)&xcat_hi[(long)m * 2048 + cidx * 8] = H.v;
    } else if (bid < 12288) {
        int j = bid - 8192;
        transpose_job(W_mix, 2048, 2048, WmixT, j & 63, j >> 6, tid, tile);
    } else if (bid < 16384) {
        int j = bid - 12288;
        transpose_job(W_out, 2048, 2048, WcatT, j & 63, j >> 6, tid, tile);
    } else if (bid < 20480) {
        int j = bid - 16384;
        transpose_job(W_gc + 2048ull * 2048ull, 2048, 2048, WgcbT, j & 63, j >> 6, tid, tile);
    } else if (bid < 22528) {
        int j = bid - 20480;
        transpose_job(W_gate, 2048, 1024, WgateT, j & 31, j >> 5, tid, tile);
    } else if (bid < 24576) {
        int g = (bid - 22528) * 256 + tid;
        int m = g >> 8, cidx = g & 255;
        int q = (cidx ^ (m >> 1)) & 3;
        int korig = ((cidx >> 2) << 5) + (q << 3);
        const float* p = W_out + (long)m * 2048 + korig;
        float4 v0 = *(const float4*)p;
        float4 v1 = *(const float4*)(p + 4);
        float vv[8] = {v0.x, v0.y, v0.z, v0.w, v1.x, v1.y, v1.z, v1.w};
        union { short8 v; ushort_t u[8]; } H;
#pragma unroll
        for (int j2 = 0; j2 < 8; j2++) H.u[j2] = f2bf_rne(vv[j2]);
        *(short8*)&Wout_rows[(long)m * 2048 + cidx * 8] = H.v;
    } else {
        int idx = (bid - 24576) * 256 + tid;
        if (idx < 2048) b_cat[idx] = b_out[idx];
        else if (idx < 3072) b_cat[idx] = b_gate[idx - 2048];
        else if (idx < 5120) b_eff[idx - 3072] = b_gc[idx - 3072];
    }
}

// ---------------- k-sliced gemv with atomic reduce (out must be pre-initialized) ----------------
__global__ void gemv_atomic(const float* __restrict__ v, const float* __restrict__ W,
                            float* __restrict__ out, int K, int N) {
    int n = blockIdx.x * 256 + threadIdx.x;
    int kn = K >> 3;
    int k0 = blockIdx.y * kn;
    float s = 0.f;
    for (int k = k0; k < k0 + kn; k++) s += v[k] * W[(long)k * N + n];
    atomicAdd(&out[n], s);
}

// ---------------- big GEMM: 512 threads, tile 256x256, BK=32, 8 waves (2Mx4N) ----------------
// 3-buffer LDS (96 KB), counted vmcnt(4), one raw barrier per K-step, depth-2 prefetch.
// OUTMODE 1: f32 + sigmoid-gate for col0>=2048. 3: bf16 plain rows.
template <int OUTMODE>
__global__ __launch_bounds__(512, 2) void gemm256(
    const ushort_t* __restrict__ Ahi,
    const ushort_t* __restrict__ Bhi,
    const float* __restrict__ bias,
    void* __restrict__ Cout, long ldc, int K) {
    // per buffer: A 256x32 (8192 ushorts) + B 256x32 (8192) = 16384 ushorts (32 KB)
    __shared__ ushort_t lds[3][16384];

    const int tid = threadIdx.x;
    const int lane = tid & 63;
    const int wave = tid >> 6;              // 0..7
    const int wr = wave >> 2, wc = wave & 3;  // 2M x 4N
    const int lr = lane & 15, kc = lane >> 4;
    const int nwg = gridDim.x * gridDim.y;
    const int orig = blockIdx.y * gridDim.x + blockIdx.x;
    const int q8 = nwg >> 3;
    const int w = (orig & 7) * q8 + (orig >> 3);
    const int row0 = (w / gridDim.x) * 256, col0 = (w % gridDim.x) * 256;

    f32x4 acc[8][4] = {};

    auto stage = [&](int buf, int kt) {
        const long kbase = (long)kt * 32;
        // A: 1024 chunks (256 rows x 4); 2 per thread
#pragma unroll
        for (int j = 0; j < 2; j++) {
            int c = j * 512 + tid;
            gld16(Ahi + (long)(row0 + (c >> 2)) * K + kbase + (c & 3) * 8,
                  &lds[buf][c * 8]);
        }
        // B: 1024 chunks (256 rows x 4); 2 per thread
#pragma unroll
        for (int j = 0; j < 2; j++) {
            int c = j * 512 + tid;
            gld16(Bhi + (long)(col0 + (c >> 2)) * K + kbase + (c & 3) * 8,
                  &lds[buf][8192 + c * 8]);
        }
    };

    const int nkt = K >> 5;
    stage(0, 0);
    stage(1, 1);
    int cur = 0;
    for (int kt = 0; kt < nkt; kt++) {
        if (kt + 1 < nkt) {
            asm volatile("s_waitcnt vmcnt(4)" ::: "memory");  // tile kt landed; kt+1 in flight
        } else {
            asm volatile("s_waitcnt vmcnt(0)" ::: "memory");
        }
        __builtin_amdgcn_sched_barrier(0);
        __builtin_amdgcn_s_barrier();
        __builtin_amdgcn_sched_barrier(0);
        if (kt + 2 < nkt) stage((cur + 2) % 3, kt + 2);

        short8 ahi[8], bhi[4];
#pragma unroll
        for (int mi = 0; mi < 8; mi++) {
            int r = wr * 128 + mi * 16 + lr;
            int idx = (r * 32 + kc * 8) ^ (((r >> 1) & 3) << 3);
            ahi[mi] = *(const short8*)&lds[cur][idx];
        }
#pragma unroll
        for (int ni = 0; ni < 4; ni++) {
            int r = wc * 64 + ni * 16 + lr;
            int idx = (r * 32 + kc * 8) ^ (((r >> 1) & 3) << 3);
            bhi[ni] = *(const short8*)&lds[cur][8192 + idx];
        }
        __builtin_amdgcn_s_setprio(1);
#pragma unroll
        for (int mi = 0; mi < 8; mi++)
#pragma unroll
            for (int ni = 0; ni < 4; ni++)
                acc[mi][ni] = __builtin_amdgcn_mfma_f32_16x16x32_bf16(ahi[mi], bhi[ni], acc[mi][ni], 0, 0, 0);
        __builtin_amdgcn_s_setprio(0);
        cur = (cur + 1) % 3;
    }

    const bool gate_blk = (OUTMODE == 1) && (col0 >= 2048);
    float bv[4];
#pragma unroll
    for (int ni = 0; ni < 4; ni++) bv[ni] = bias ? bias[col0 + wc * 64 + ni * 16 + lr] : 0.f;
#pragma unroll
    for (int mi = 0; mi < 8; mi++) {
        int rbase = row0 + wr * 128 + mi * 16 + kc * 4;
#pragma unroll
        for (int ni = 0; ni < 4; ni++) {
            int c = col0 + wc * 64 + ni * 16 + lr;
#pragma unroll
            for (int i = 0; i < 4; i++) {
                float v = acc[mi][ni][i] + bv[ni];
                if constexpr (OUTMODE == 3) {
                    ((ushort_t*)Cout)[(long)(rbase + i) * ldc + c] = f2bf_rne(v);
                } else {
                    if (gate_blk) v = 0.98f / (1.0f + __expf(-v)) + 0.01f;
                    ((float*)Cout)[(long)(rbase + i) * ldc + c] = v;
                }
            }
        }
    }
}

// ---------------- small GEMM (weight folds): tile 256x128, proven R10 kernel ----------------
// OUTMODE 2: bf16 swizzled rows.
template <int OUTMODE, bool ADDM>
__global__ __launch_bounds__(256, 2) void gemm_bf16(
    const ushort_t* __restrict__ Ahi,
    const ushort_t* __restrict__ Bhi,
    const float* __restrict__ bias,
    const float* __restrict__ Cadd, int ldadd,
    void* __restrict__ Cout, long ldc, int K) {
    __shared__ ushort_t lds[3][12288];

    const int tid = threadIdx.x;
    const int lane = tid & 63;
    const int wave = tid >> 6;
    const int wr = wave >> 1, wc = wave & 1;
    const int lr = lane & 15, kc = lane >> 4;
    const int nwg = gridDim.x * gridDim.y;
    const int orig = blockIdx.y * gridDim.x + blockIdx.x;
    const int q8 = nwg >> 3;
    const int w = (orig & 7) * q8 + (orig >> 3);
    const int row0 = (w / gridDim.x) * 256, col0 = (w % gridDim.x) * 128;

    f32x4 acc[8][4] = {};

    auto stage = [&](int buf, int kt) {
        const long kbase = (long)kt * 32;
#pragma unroll
        for (int j = 0; j < 4; j++) {
            int c = j * 256 + tid;
            gld16(Ahi + (long)(row0 + (c >> 2)) * K + kbase + (c & 3) * 8,
                  &lds[buf][c * 8]);
        }
#pragma unroll
        for (int j = 0; j < 2; j++) {
            int c = j * 256 + tid;
            gld16(Bhi + (long)(col0 + (c >> 2)) * K + kbase + (c & 3) * 8,
                  &lds[buf][8192 + c * 8]);
        }
    };

    const int nkt = K >> 5;
    stage(0, 0);
    stage(1, 1);
    int cur = 0;
    for (int kt = 0; kt < nkt; kt++) {
        if (kt + 1 < nkt) {
            asm volatile("s_waitcnt vmcnt(6)" ::: "memory");
        } else {
            asm volatile("s_waitcnt vmcnt(0)" ::: "memory");
        }
        __builtin_amdgcn_sched_barrier(0);
        __builtin_amdgcn_s_barrier();
        __builtin_amdgcn_sched_barrier(0);
        if (kt + 2 < nkt) stage((cur + 2) % 3, kt + 2);

        short8 ahi[8], bhi[4];
#pragma unroll
        for (int mi = 0; mi < 8; mi++) {
            int r = wr * 128 + mi * 16 + lr;
            int idx = (r * 32 + kc * 8) ^ (((r >> 1) & 3) << 3);
            ahi[mi] = *(const short8*)&lds[cur][idx];
        }
#pragma unroll
        for (int ni = 0; ni < 4; ni++) {
            int r = wc * 64 + ni * 16 + lr;
            int idx = (r * 32 + kc * 8) ^ (((r >> 1) & 3) << 3);
            bhi[ni] = *(const short8*)&lds[cur][8192 + idx];
        }
        __builtin_amdgcn_s_setprio(1);
#pragma unroll
        for (int mi = 0; mi < 8; mi++)
#pragma unroll
            for (int ni = 0; ni < 4; ni++)
                acc[mi][ni] = __builtin_amdgcn_mfma_f32_16x16x32_bf16(ahi[mi], bhi[ni], acc[mi][ni], 0, 0, 0);
        __builtin_amdgcn_s_setprio(0);
        cur = (cur + 1) % 3;
    }

    float bv[4];
#pragma unroll
    for (int ni = 0; ni < 4; ni++) bv[ni] = bias ? bias[col0 + wc * 64 + ni * 16 + lr] : 0.f;
#pragma unroll
    for (int mi = 0; mi < 8; mi++) {
        int rbase = row0 + wr * 128 + mi * 16 + kc * 4;
#pragma unroll
        for (int ni = 0; ni < 4; ni++) {
            int c = col0 + wc * 64 + ni * 16 + lr;
#pragma unroll
            for (int i = 0; i < 4; i++) {
                float v = acc[mi][ni][i] + bv[ni];
                if constexpr (ADDM) v += Cadd[(long)(rbase + i) * ldadd + c];
                if constexpr (OUTMODE == 2) {
                    ((ushort_t*)Cout)[(long)(rbase + i) * ldc + swz_col(rbase + i, c)] = f2bf_rne(v);
                } else {
                    ((float*)Cout)[(long)(rbase + i) * ldc + c] = v;
                }
            }
        }
    }
}

// ---------------- scan ----------------
__device__ __forceinline__ void step_coefs(float lre, float lim, float dt,
                                           float& are, float& aim,
                                           float& fre, float& fim) {
    float zr = lre * dt, zi = lim * dt;
    float ex = __expf(zr);
    float er = ex - 1.0f;
    float hh = 0.5f * zi;
    float s = __sinf(hh), c = __cosf(hh);
    float s2s = 2.0f * s * s;
    float cy = 1.0f - s2s;
    float sy = 2.0f * s * c;
    are = ex * cy;
    aim = ex * sy;
    float nr = er * cy - s2s;
    float ni = ex * sy;
    float r2 = zr * zr + zi * zi;
    float pr, pi;
    if (r2 > 1e-14f) {
        float inv = 1.0f / r2;
        pr = (nr * zr + ni * zi) * inv;
        pi = (ni * zr - nr * zi) * inv;
    } else {
        pr = 1.0f + 0.5f * zr;
        pi = 0.5f * zi;
    }
    fre = dt * pr;
    fim = dt * pi;
}

__device__ __forceinline__ void lam_of(const float* dre, const float* dim, int d,
                                       float& lre, float& lim) {
    float x = dre[d];
    float sp = fmaxf(x, 0.0f) + log1pf(expf(-fabsf(x)));
    lre = -sp;
    lim = dim[d];
}

__global__ void scan_phase1(const ushort_t* __restrict__ x_in,
                            const float* __restrict__ dt_seq,
                            const float* __restrict__ decay_re,
                            const float* __restrict__ decay_im,
                            float4* __restrict__ S) {
    int gw = (blockIdx.x * blockDim.x + threadIdx.x) >> 6;
    int lane = threadIdx.x & 63;
    int d64 = gw & 15;
    int c = (gw >> 4) & (NC - 1);
    int b = gw >> 10;
    int d = d64 * 64 + lane;
    float lre, lim;
    lam_of(decay_re, decay_im, d, lre, lim);
    float Are = 1.f, Aim = 0.f, Bre = 0.f, Bim = 0.f;
    for (int j = 0; j < CT; j++) {
        int t = c * CT + j;
        float dt = dt_seq[b * T_SEQ + t];
        float are, aim, fre, fim;
        step_coefs(lre, lim, dt, are, aim, fre, fim);
        size_t off = ((size_t)(b * T_SEQ + t)) * 2048;
        float xr = bf2f(x_in[off + d]);
        float xi = bf2f(x_in[off + 1024 + d]);
        float xsr = xr * fre - xi * fim;
        float xsi = xr * fim + xi * fre;
        float nbr = are * Bre - aim * Bim + xsr;
        float nbi = are * Bim + aim * Bre + xsi;
        Bre = nbr; Bim = nbi;
        float nar = are * Are - aim * Aim;
        float nai = are * Aim + aim * Are;
        Are = nar; Aim = nai;
    }
    S[(size_t)(b * NC + c) * D_DIM + d] = make_float4(Are, Aim, Bre, Bim);
}

__global__ void scan_phase2(const float4* __restrict__ S,
                            const float* __restrict__ h0_re,
                            const float* __restrict__ h0_im,
                            float2* __restrict__ Pre) {
    int idx = blockIdx.x * blockDim.x + threadIdx.x;
    int b = idx >> 10, d = idx & 1023;
    float Are = 1.f, Aim = 0.f;
    float Bre = h0_re[d], Bim = h0_im[d];
    for (int c = 0; c < NC; c++) {
        Pre[(size_t)(b * NC + c) * D_DIM + d] = make_float2(Bre, Bim);
        float4 s = S[(size_t)(b * NC + c) * D_DIM + d];
        float nAre = s.x * Are - s.y * Aim;
        float nAim = s.x * Aim + s.y * Are;
        float nBre = s.x * Bre - s.y * Bim + s.z;
        float nBim = s.x * Bim + s.y * Bre + s.w;
        Are = nAre; Aim = nAim; Bre = nBre; Bim = nBim;
    }
}

__global__ void scan_phase3(const ushort_t* __restrict__ x_in,
                            const float* __restrict__ dt_seq,
                            const float* __restrict__ decay_re,
                            const float* __restrict__ decay_im,
                            const float2* __restrict__ Pre,
                            ushort_t* __restrict__ sthi) {
    int gw = (blockIdx.x * blockDim.x + threadIdx.x) >> 6;
    int lane = threadIdx.x & 63;
    int d64 = gw & 15;
    int c = (gw >> 4) & (NC - 1);
    int b = gw >> 10;
    int d = d64 * 64 + lane;
    float lre, lim;
    lam_of(decay_re, decay_im, d, lre, lim);
    float2 h = Pre[(size_t)(b * NC + c) * D_DIM + d];
    float hre = h.x, him = h.y;
    for (int j = 0; j < CT; j++) {
        int t = c * CT + j;
        int m = b * T_SEQ + t;
        float dt = dt_seq[m];
        float are, aim, fre, fim;
        step_coefs(lre, lim, dt, are, aim, fre, fim);
        size_t off = ((size_t)m) * 2048;
        float xr = bf2f(x_in[off + d]);
        float xi = bf2f(x_in[off + 1024 + d]);
        float xsr = xr * fre - xi * fim;
        float xsi = xr * fim + xi * fre;
        float nre = are * hre - aim * him + xsr;
        float nim = are * him + aim * hre + xsi;
        hre = nre; him = nim;
        long idx = (long)m * 2048 + swz_col(m, d);
        sthi[idx] = f2bf_rne(hre);
        sthi[idx + 1024] = f2bf_rne(him);
    }
}

extern "C" void kernel_launch(void* const* d_in, const int* in_sizes, int n_in,
                              void* d_out, int out_size, void* d_ws, size_t ws_size,
                              hipStream_t stream) {
    const float* x_re = (const float*)d_in[0];
    const float* x_im = (const float*)d_in[1];
    const float* dt_seq = (const float*)d_in[2];
    const float* decay_re = (const float*)d_in[3];
    const float* decay_im = (const float*)d_in[4];
    const float* h0_re = (const float*)d_in[5];
    const float* h0_im = (const float*)d_in[6];
    const float* W_mix = (const float*)d_in[7];
    const float* b_mix = (const float*)d_in[8];
    const float* W_out = (const float*)d_in[9];
    const float* b_out = (const float*)d_in[10];
    const float* W_gc = (const float*)d_in[11];
    const float* b_gc = (const float*)d_in[12];
    const float* W_gate = (const float*)d_in[13];
    const float* b_gate = (const float*)d_in[14];
    float* out = (float*)d_out;

    char* ws = (char*)d_ws;
    const unsigned long MB = 1048576ull;
    ushort_t* x_inb = (ushort_t*)ws;                   // 32 MB (bf16 x_in)
    ushort_t* Wout_rows = (ushort_t*)(ws + 32 * MB);   // 8 MB
    ushort_t* WgcbT = (ushort_t*)(ws + 40 * MB);       // 8 MB
    ushort_t* WgateT = (ushort_t*)(ws + 48 * MB);      // 4 MB
    ushort_t* tmp1_hi = (ushort_t*)(ws + 52 * MB);     // 8 MB
    ushort_t* xcat_hi = (ushort_t*)(ws + 64 * MB);     // 32 MB
    ushort_t* state_hi = xcat_hi;                      // time-aliased
    float4* S = (float4*)(ws + 128 * MB);              // 4 MB
    float2* Pre = (float2*)(ws + 132 * MB);            // 2 MB
    ushort_t* WmixT = (ushort_t*)(ws + 134 * MB);      // 8 MB
    ushort_t* WcatT = (ushort_t*)(ws + 142 * MB);      // 12 MB (3072 x 2048)
    float* b_cat = (float*)(ws + 154 * MB);            // 12 KB
    float* b_eff = (float*)(ws + 154 * MB + 16384);    // 8 KB

    dim3 blk(256);

    // 1. all transposes/conversions/bias-inits in one launch
    prep_all<<<dim3(24596), blk, 0, stream>>>(
        W_mix, W_out, W_gc, W_gate, x_re, x_im, b_out, b_gate, b_gc,
        WmixT, WcatT, WgcbT, WgateT, Wout_rows, xcat_hi, b_cat, b_eff);

    // 2. b_eff += b_out @ W_gc_bot   (b_eff pre-init to b_gc)
    gemv_atomic<<<dim3(8, 8), blk, 0, stream>>>(b_out, W_gc + 2048ull * 2048ull, b_eff, 2048, 2048);

    // 3. tmp1 = W_out @ W_gc_bot + W_gc_top  -> bf16 swizzled rows (M=2048, N=2048)
    gemm_bf16<2, true><<<dim3(16, 8), blk, 0, stream>>>(
        Wout_rows, WgcbT, nullptr, W_gc, 2048, tmp1_hi, 2048, 2048);

    // 4. W_totalT = W_gateT @ tmp1T  -> WcatT rows 2048..3071 (M=1024, N=2048)
    gemm_bf16<2, false><<<dim3(16, 4), blk, 0, stream>>>(
        WgateT, tmp1_hi, nullptr, nullptr, 0,
        WcatT + 2048ull * 2048ull, 2048, 2048);

    // 5. b_cat[2048:] += b_eff @ W_gate   (pre-init to b_gate)
    gemv_atomic<<<dim3(4, 8), blk, 0, stream>>>(b_eff, W_gate, b_cat + 2048, 2048, 1024);

    // 6. x_in(bf16) = xcat @ W_mix + b_mix   (M=8192, N=2048) - 512-thread kernel
    gemm256<3><<<dim3(8, 32), dim3(512), 0, stream>>>(
        xcat_hi, WmixT, b_mix, x_inb, 2048, 2048);

    // 7-9. scan
    scan_phase1<<<dim3(1024), blk, 0, stream>>>(x_inb, dt_seq, decay_re, decay_im, S);
    scan_phase2<<<dim3(16), blk, 0, stream>>>(S, h0_re, h0_im, Pre);
    scan_phase3<<<dim3(1024), blk, 0, stream>>>(x_inb, dt_seq, decay_re, decay_im, Pre,
                                                state_hi);

    // 10. [src | gate] = state @ [W_outT | W_totalT]^T + b_cat (M=8192, N=3072) - 512-thr
    gemm256<1><<<dim3(12, 32), dim3(512), 0, stream>>>(
        state_hi, WcatT, b_cat, out, 3072, 2048);
}